// Round 5
// baseline (16335.048 us; speedup 1.0000x reference)
//
#include <hip/hip_runtime.h>

// LSTM: T=512, B=64, IN=512, H=1024, 4H=4096, LAYERS=4, OUT=1
// R5: pure dataflow sync — no global barrier. 256 WGs (layer x 64 unit-WGs),
// each runs its own t=0..511 loop and waits only on flags it reads:
//   own-layer FLAG[l][*] >= t       (h_l(t-1) ready)
//   prev-layer FLAG[l-1][*] >= t+1  (h_{l-1}(t) ready; layer0 reads static XP)
//   back-pressure FLAG[l+1][*] >= t-31 (ring depth 32)
// Own-half GEMM runs before the cross-layer wait (hides it). Busy-spin polls,
// flags packed 64/block (poll = 2 cache lines). Layer->XCD-pair placement
// heuristic via blockIdx mapping (perf only). W register-stationary, 32x32x16.

typedef unsigned short u16;
typedef short bf16x8 __attribute__((ext_vector_type(8)));
typedef float f32x4 __attribute__((ext_vector_type(4)));
typedef float f32x16 __attribute__((ext_vector_type(16)));

__device__ __forceinline__ u16 f2bf(float f) {
  unsigned u = __float_as_uint(f);
  return (u16)((u + 0x7FFFu + ((u >> 16) & 1u)) >> 16);   // RNE
}
__device__ __forceinline__ float bf2f(u16 s) {
  return __uint_as_float(((unsigned)s) << 16);
}
__device__ __forceinline__ bf16x8 ld8(const u16* p) {
  uint4 v = *(const uint4*)p;
  return __builtin_bit_cast(bf16x8, v);
}
__device__ __forceinline__ float sigf(float x) {
  x = fminf(fmaxf(x, -30.f), 30.f);
  return 1.f / (1.f + __expf(-x));
}
__device__ __forceinline__ float tanhf_(float x) {
  x = fminf(fmaxf(x, -15.f), 15.f);
  float e = __expf(-2.f * x);
  return (1.f - e) / (1.f + e);
}

#define AT_LD(p) __hip_atomic_load((p), __ATOMIC_RELAXED, __HIP_MEMORY_SCOPE_AGENT)
#define AT_ST(p, v) __hip_atomic_store((p), (v), __ATOMIC_RELAXED, __HIP_MEMORY_SCOPE_AGENT)

// ---------------- repack: W -> WCAT[l][4096][2048] bf16 ----------------
__global__ void repack_w(const float* __restrict__ wih0, const float* __restrict__ wihr,
                         const float* __restrict__ whh, u16* __restrict__ WCAT) {
  size_t i = (size_t)blockIdx.x * 256 + threadIdx.x;   // 33554432 total
  int l = (int)(i >> 23);
  int r = (int)(i >> 11) & 4095;
  int c = (int)i & 2047;
  int Kx = l ? 1024 : 512;
  float v = 0.f;
  if (c < Kx) v = l ? wihr[((size_t)(l - 1) * 4096 + r) * 1024 + c]
                    : wih0[(size_t)r * 512 + c];
  else if (c < Kx + 1024) v = whh[((size_t)l * 4096 + r) * 1024 + (c - Kx)];
  WCAT[i] = f2bf(v);
}

// ---------------- repack: x -> XP[t][kc(64)][b(64)][8] bf16 ----------------
__global__ void repack_x(const float* __restrict__ x, u16* __restrict__ XP) {
  int i = blockIdx.x * 256 + threadIdx.x;   // 2097152 total
  int t = i >> 12, r = i & 4095, kc = r >> 6, b = r & 63;
  const float* src = x + ((size_t)t * 64 + b) * 512 + kc * 8;
  float4 v0 = *(const float4*)src, v1 = *(const float4*)(src + 4);
  u16 o[8] = {f2bf(v0.x), f2bf(v0.y), f2bf(v0.z), f2bf(v0.w),
              f2bf(v1.x), f2bf(v1.y), f2bf(v1.z), f2bf(v1.w)};
  *(uint4*)(XP + ((size_t)(t * 64 + kc) * 64 + b) * 8) = *(uint4*)o;
}

__global__ void bias_add(const float* __restrict__ a, const float* __restrict__ b,
                         float* __restrict__ o) {
  int i = blockIdx.x * blockDim.x + threadIdx.x;   // 16384 total
  o[i] = a[i] + b[i];
}

// ---------------- dataflow pipelined recurrence ----------------
// WG (layer, w64): owns units [16*w64, +16) -> 64 gate-rows. 8 waves =
// (ks 0..3, nh 0..1). K interleave: frag f = j*4 + ks. Cross half (x or
// h_{l-1}): f in [0, 4*NFX); own half (h_l): f in [4*NFX, 4*NFX+64).
// NFX = 8 (layer0, K_x=512) or 16 (K_x=1024). Own frags/wave = 16 always.
template <int NFX>
__device__ __forceinline__ void run_pipe(
    int layer, int w64, const u16* __restrict__ WCAT, const u16* __restrict__ XP,
    u16* __restrict__ HR, u16* __restrict__ HOUT, const float* __restrict__ BIAS,
    unsigned* __restrict__ FLAG, float* R) {
  const int tid = threadIdx.x;
  const int lane = tid & 63, wv = tid >> 6;
  const int ks = wv & 3, nh = wv >> 2;
  const int l31 = lane & 31, lhi = lane >> 5;
  const int FX = NFX * 4;

  // ---- W preload (persistent VGPRs) ----
  bf16x8 wfc[NFX], wfo[16];
  {
    const int lr = nh * 32 + l31;
    const int grow = (lr >> 4) * 1024 + 16 * w64 + (lr & 15);
    const u16* wrow = WCAT + ((size_t)layer * 4096 + grow) * 2048;
#pragma unroll
    for (int j = 0; j < NFX; ++j) wfc[j] = ld8(wrow + (j * 4 + ks) * 16 + lhi * 8);
#pragma unroll
    for (int j = 0; j < 16; ++j) wfo[j] = ld8(wrow + (FX + j * 4 + ks) * 16 + lhi * 8);
  }

  const int u = tid & 15, bp = tid >> 4;       // gating: (batch bp & bp+32, unit u)
  const int col = 16 * w64 + u;
  float c0 = 0.f, c1 = 0.f;
  const float bi = BIAS[layer * 4096 + col];
  const float bf_ = BIAS[layer * 4096 + 1024 + col];
  const float bg = BIAS[layer * 4096 + 2048 + col];
  const float bo = BIAS[layer * 4096 + 3072 + col];

  const int lane_base = (lhi * 64 + l31) * 8;  // mtile0; mtile1 at +256 elems
  u16* HRL = HR + (size_t)layer * 2097152;
  const u16* HRm1 = (layer > 0) ? HR + (size_t)(layer - 1) * 2097152 : XP;
  const int lrD = nh * 32 + l31;               // C/D col -> local gate-row

  for (int t = 0; t < 512; ++t) {
    *(f32x4*)&R[tid * 8] = f32x4{0.f, 0.f, 0.f, 0.f};
    *(f32x4*)&R[tid * 8 + 4] = f32x4{0.f, 0.f, 0.f, 0.f};
    // ---- wait: own layer done t-1; back-pressure on consumer ----
    if (wv == 0) {
      for (;;) {
        int f1 = (int)AT_LD(&FLAG[layer * 64 + lane]);
        bool ok = (f1 >= t);
        if (layer < 3) {
          int f2 = (int)AT_LD(&FLAG[(layer + 1) * 64 + lane]);
          ok &= (f2 >= t - 31);
        }
        if (__ballot(ok) == ~0ull) break;
      }
    }
    __syncthreads();                           // also covers R zeros

    f32x16 acc0 = {}, acc1 = {};
    // ---- own half: h_l(t-1), ring slot (t-1)&31 ----
    {
      const u16* PO = HRL + (size_t)((t - 1) & 31) * 65536 + lane_base;
      uint4 a0[4], a1[4];
#pragma unroll
      for (int p = 0; p < 4; ++p) {
        const u16* ap = PO + (size_t)(p * 4 + ks) * 1024;
        a0[p] = *(const uint4*)ap; a1[p] = *(const uint4*)(ap + 256);
      }
#pragma unroll
      for (int j = 0; j < 16; ++j) {
        uint4 ca = a0[j & 3], cb = a1[j & 3];
        if (j + 4 < 16) {
          const u16* ap = PO + (size_t)((j + 4) * 4 + ks) * 1024;
          a0[j & 3] = *(const uint4*)ap; a1[j & 3] = *(const uint4*)(ap + 256);
        }
        acc0 = __builtin_amdgcn_mfma_f32_32x32x16_bf16(
            __builtin_bit_cast(bf16x8, ca), wfo[j], acc0, 0, 0, 0);
        acc1 = __builtin_amdgcn_mfma_f32_32x32x16_bf16(
            __builtin_bit_cast(bf16x8, cb), wfo[j], acc1, 0, 0, 0);
      }
    }
    // ---- wait: producer layer done t (usually already true) ----
    if (layer > 0 && wv == 0) {
      for (;;) {
        int f = (int)AT_LD(&FLAG[(layer - 1) * 64 + lane]);
        if (__ballot(f >= t + 1) == ~0ull) break;
      }
    }
    __syncthreads();
    // ---- cross half: h_{l-1}(t) slot t&31, or x(t) ----
    {
      const u16* PC = HRm1 + ((layer > 0) ? (size_t)(t & 31) * 65536
                                          : (size_t)t * 32768) + lane_base;
      uint4 a0[4], a1[4];
#pragma unroll
      for (int p = 0; p < 4; ++p) {
        const u16* ap = PC + (size_t)(p * 4 + ks) * 1024;
        a0[p] = *(const uint4*)ap; a1[p] = *(const uint4*)(ap + 256);
      }
#pragma unroll
      for (int j = 0; j < NFX; ++j) {
        uint4 ca = a0[j & 3], cb = a1[j & 3];
        if (j + 4 < NFX) {
          const u16* ap = PC + (size_t)((j + 4) * 4 + ks) * 1024;
          a0[j & 3] = *(const uint4*)ap; a1[j & 3] = *(const uint4*)(ap + 256);
        }
        acc0 = __builtin_amdgcn_mfma_f32_32x32x16_bf16(
            __builtin_bit_cast(bf16x8, ca), wfc[j], acc0, 0, 0, 0);
        acc1 = __builtin_amdgcn_mfma_f32_32x32x16_bf16(
            __builtin_bit_cast(bf16x8, cb), wfc[j], acc1, 0, 0, 0);
      }
    }
    // ---- k-partial reduce in LDS ----
#pragma unroll
    for (int r = 0; r < 16; ++r) {
      int m = (r & 3) + 8 * (r >> 2) + 4 * lhi;      // 32x32 C/D row map (m101)
      atomicAdd(&R[m * 64 + lrD], acc0[r]);
      atomicAdd(&R[(32 + m) * 64 + lrD], acc1[r]);
    }
    __syncthreads();
    // ---- gating ----
    {
      float p0i = R[bp * 64 + u] + bi, p0f = R[bp * 64 + 16 + u] + bf_;
      float p0g = R[bp * 64 + 32 + u] + bg, p0o = R[bp * 64 + 48 + u] + bo;
      float p1i = R[(bp + 32) * 64 + u] + bi, p1f = R[(bp + 32) * 64 + 16 + u] + bf_;
      float p1g = R[(bp + 32) * 64 + 32 + u] + bg, p1o = R[(bp + 32) * 64 + 48 + u] + bo;
      c0 = sigf(p0f) * c0 + sigf(p0i) * tanhf_(p0g);
      float h0 = sigf(p0o) * tanhf_(c0);
      c1 = sigf(p1f) * c1 + sigf(p1i) * tanhf_(p1g);
      float h1 = sigf(p1o) * tanhf_(c1);
      u16 hb0 = f2bf(h0), hb1 = f2bf(h1);
      unsigned n0 = (unsigned)(u16)__shfl_down((int)(unsigned)hb0, 1, 64);
      unsigned n1 = (unsigned)(u16)__shfl_down((int)(unsigned)hb1, 1, 64);
      if ((u & 1) == 0) {
        unsigned pk0 = (unsigned)hb0 | (n0 << 16);
        unsigned pk1 = (unsigned)hb1 | (n1 << 16);
        u16* slot = HRL + (size_t)(t & 31) * 65536;
        size_t e0 = ((size_t)(col >> 3) * 64 + bp) * 8 + (col & 7);
        AT_ST((unsigned*)(slot + e0), pk0);
        AT_ST((unsigned*)(slot + e0 + 256), pk1);    // batch +32
        if (layer == 3 && bp == 31)                  // batch 63 for the head
          *(unsigned*)(HOUT + (size_t)t * 1024 + col) = pk1;
      }
    }
    __syncthreads();   // per-wave vmcnt(0) drain: ring stores at coherence point
    if (tid == 0) AT_ST(&FLAG[layer * 64 + w64], (unsigned)(t + 1));
  }
}

__global__ __launch_bounds__(512, 2) void lstm_pipe(
    const u16* __restrict__ WCAT, const u16* __restrict__ XP,
    u16* __restrict__ HR, u16* __restrict__ HOUT,
    const float* __restrict__ BIAS, unsigned* __restrict__ FLAG) {
  __shared__ float R[64 * 64];
  const int b = blockIdx.x;
  // layer -> XCD pair (heuristic xcd = blockIdx % 8): layers 0..3 on pairs
  const int layer = (b & 7) >> 1;
  const int w64 = (b >> 3) * 2 + (b & 1);
  if (layer == 0) run_pipe<8>(0, w64, WCAT, XP, HR, HOUT, BIAS, FLAG, R);
  else            run_pipe<16>(layer, w64, WCAT, XP, HR, HOUT, BIAS, FLAG, R);
}

// ---------------- head: out[t] = sigmoid(h3[t][63][:]) . fcw + fcb ----------------
__global__ void lstm_head(const u16* __restrict__ Hl, const float* __restrict__ fcw,
                          const float* __restrict__ fcb, float* __restrict__ out) {
  int t = blockIdx.x, tid = threadIdx.x;
  const u16* hrow = Hl + (size_t)t * 1024;
  float s = 0.f;
  for (int j = tid; j < 1024; j += 256)
    s += sigf(bf2f(hrow[j])) * fcw[j];
  for (int o = 32; o; o >>= 1) s += __shfl_down(s, o, 64);
  __shared__ float red[4];
  if ((tid & 63) == 0) red[tid >> 6] = s;
  __syncthreads();
  if (tid == 0) out[t] = red[0] + red[1] + red[2] + red[3] + fcb[0];
}

// ---------------- launch ----------------
extern "C" void kernel_launch(void* const* d_in, const int* in_sizes, int n_in,
                              void* d_out, int out_size, void* d_ws, size_t ws_size,
                              hipStream_t stream) {
  const float* x    = (const float*)d_in[0];
  const float* wih0 = (const float*)d_in[1];
  const float* wihr = (const float*)d_in[2];
  const float* whh  = (const float*)d_in[3];
  const float* bih  = (const float*)d_in[4];
  const float* bhh  = (const float*)d_in[5];
  const float* fcw  = (const float*)d_in[6];
  const float* fcb  = (const float*)d_in[7];
  float* out = (float*)d_out;

  char* ws = (char*)d_ws;
  size_t off = 0;
  auto alc = [&](size_t b) { void* p = ws + off; off = (off + b + 255) & ~(size_t)255; return p; };
  u16* WCAT  = (u16*)alc(33554432ull * 2);   // 64 MB
  u16* XP    = (u16*)alc(16777216ull * 2);   // 32 MB
  u16* HR    = (u16*)alc(8388608ull * 2);    // 16 MB (4 layers x 32 slots x 128 KB)
  u16* HOUT  = (u16*)alc(524288ull * 2);     // 1 MB
  float* BIAS = (float*)alc(16384 * 4);
  unsigned* FLAG = (unsigned*)alc(256 * 4);  // [layer][w64] packed (poll = 2 lines)
  (void)ws_size; (void)in_sizes; (void)n_in; (void)out_size;

  hipMemsetAsync(HR, 0, 8388608ull * 2, stream);
  hipMemsetAsync(FLAG, 0, 256 * 4, stream);
  repack_w<<<dim3(131072), 256, 0, stream>>>(wih0, wihr, whh, WCAT);
  repack_x<<<dim3(8192), 256, 0, stream>>>(x, XP);
  bias_add<<<dim3(64), 256, 0, stream>>>(bih, bhh, BIAS);

  void* args[] = {&WCAT, &XP, &HR, &HOUT, &BIAS, &FLAG};
  hipLaunchCooperativeKernel((const void*)lstm_pipe, dim3(256), dim3(512),
                             args, 0, stream);

  lstm_head<<<dim3(512), 256, 0, stream>>>(HOUT, fcw, fcb, out);
}